// Round 8
// baseline (153.074 us; speedup 1.0000x reference)
//
#include <hip/hip_runtime.h>
#include <stdint.h>

#define T_STEPS  1000
#define BATCH    32
#define N_NEURON 1000
#define IN_DIM   128
#define OUT_DIM  20

typedef unsigned short ushort_t;
typedef unsigned long long ull_t;
using f32x4  = __attribute__((ext_vector_type(4))) float;
using bf16x8 = __attribute__((ext_vector_type(8))) short;

// fp32 -> bf16 (RTN-even)
static __device__ __forceinline__ ushort_t f2bf(float f) {
    unsigned u = __float_as_uint(f);
    return (ushort_t)((u + 0x7FFFu + ((u >> 16) & 1u)) >> 16);
}

// ws layout (bytes)
#define OFF_WB   0ull            // 1024*128 bf16 = 262144
#define OFF_GMAX 262144ull       // 1 float
#define OFF_FLAG 262272ull       // 32 ints
#define WS_NEED  262400ull

// ============================================================================
// Kernel 0: W_in -> bf16 (padded to 1024 rows, extra rows zeroed) + init gmax.
// ============================================================================
#define NWP4 32768     // 1024*128/4

__global__ __launch_bounds__(256) void conv_wb_kernel(
    const float* __restrict__ W, ushort_t* __restrict__ Wb,
    float* __restrict__ gmax)
{
    int idx = blockIdx.x * 256 + threadIdx.x;
    if (idx == 0) gmax[0] = 0.f;
    if (idx < NWP4) {
        ushort_t h[4];
#pragma unroll
        for (int j = 0; j < 4; ++j) {
            int widx = idx * 4 + j;
            int row  = widx >> 7;
            float f  = (row < N_NEURON) ? W[widx] : 0.f;
            h[j] = f2bf(f);
        }
        ((ushort4*)Wb)[idx] = make_ushort4(h[0], h[1], h[2], h[3]);
    }
}

// ============================================================================
// Kernel 1: max-reduced bf16 MFMA GEMM — NO output stores.
// Silence proof: w_t = a_v*w_{t-1} + (1-a_v)*I_t (w = v - V_RESET, w0 = 0)
// is a convex combination of {0, past I}, so w_max <= max(0, max I).
// Spike needs w >= 15. We compute gmax = max over all (t,b,n) of
// in_scale * (x @ W_in^T) and compare to 15 - 0.5 (bf16 error << 0.5).
// Max is invariant to MFMA fragment layout -> layout-proof.
// Block: 128 x-rows (wave owns 32 = 2 m-tiles) x 256 neurons (16 n-tiles).
// Grid (250, 4) = 1000 blocks. Zero LDS. B double-buffered.
// ============================================================================
__global__ __launch_bounds__(256, 4) void maxgemm_kernel(
    const float* __restrict__ x, const ushort_t* __restrict__ Wb,
    const float* __restrict__ in_scale_p, float* __restrict__ gmax)
{
    const int tid  = threadIdx.x;
    const int lane = tid & 63;
    const int wave = tid >> 6;
    const int quad = lane >> 4;
    const int l15  = lane & 15;
    const int m0   = blockIdx.x * 128 + wave * 32;   // < 32000 (250*128)
    const int n0   = blockIdx.y * 256;               // padded 1024 cols
    const float is = in_scale_p[0];

    // ---- A-frags: 32 consecutive rows, contiguous 16 KB region ----
    bf16x8 Af[2][4];
#pragma unroll
    for (int mt = 0; mt < 2; ++mt) {
        const float* xp = x + (size_t)(m0 + mt * 16 + l15) * IN_DIM;
        float4 lo[4], hi[4];
#pragma unroll
        for (int kb = 0; kb < 4; ++kb) {
            lo[kb] = *(const float4*)(xp + kb * 32 + quad * 8);
            hi[kb] = *(const float4*)(xp + kb * 32 + quad * 8 + 4);
        }
#pragma unroll
        for (int kb = 0; kb < 4; ++kb) {
            bf16x8 f;
            f[0] = (short)f2bf(lo[kb].x); f[1] = (short)f2bf(lo[kb].y);
            f[2] = (short)f2bf(lo[kb].z); f[3] = (short)f2bf(lo[kb].w);
            f[4] = (short)f2bf(hi[kb].x); f[5] = (short)f2bf(hi[kb].y);
            f[6] = (short)f2bf(hi[kb].z); f[7] = (short)f2bf(hi[kb].w);
            Af[mt][kb] = f;
        }
    }

    // ---- 16 n-tiles, B double-buffered ----
    bf16x8 Bc[4], Bn[4];
#pragma unroll
    for (int kb = 0; kb < 4; ++kb)
        Bc[kb] = *(const bf16x8*)(Wb + (size_t)(n0 + l15) * IN_DIM +
                                  kb * 32 + quad * 8);
    float mx = 0.f;   // init 0 keeps mx >= 0 (bound uses max(0, I) anyway)

#pragma unroll
    for (int tj = 0; tj < 16; ++tj) {
        if (tj < 15) {
            const int np = n0 + (tj + 1) * 16;
#pragma unroll
            for (int kb = 0; kb < 4; ++kb)
                Bn[kb] = *(const bf16x8*)(Wb + (size_t)(np + l15) * IN_DIM +
                                          kb * 32 + quad * 8);
        }
        f32x4 a0 = (f32x4){0.f, 0.f, 0.f, 0.f};
        f32x4 a1 = (f32x4){0.f, 0.f, 0.f, 0.f};
#pragma unroll
        for (int kb = 0; kb < 4; ++kb) {
            a0 = __builtin_amdgcn_mfma_f32_16x16x32_bf16(Af[0][kb], Bc[kb], a0, 0, 0, 0);
            a1 = __builtin_amdgcn_mfma_f32_16x16x32_bf16(Af[1][kb], Bc[kb], a1, 0, 0, 0);
        }
#pragma unroll
        for (int i = 0; i < 4; ++i) {
            mx = fmaxf(mx, is * a0[i]);
            mx = fmaxf(mx, is * a1[i]);
        }
#pragma unroll
        for (int kb = 0; kb < 4; ++kb) Bc[kb] = Bn[kb];
    }

    // ---- reduce: lanes -> wave -> one device atomic (mx >= 0: int-bits ok) ----
#pragma unroll
    for (int off = 32; off > 0; off >>= 1)
        mx = fmaxf(mx, __shfl_xor(mx, off, 64));
    if (lane == 0)
        atomicMax((int*)gmax, __float_as_int(mx));
}

// ============================================================================
// Kernel 2: resolve. gmax < 14.5  =>  no spike anywhere (all batches) =>
// avg == 0 => out = b_out bitwise, flags 0. Else flags 1 (exact sim runs).
// ============================================================================
__global__ __launch_bounds__(256) void resolve_kernel(
    const float* __restrict__ gmax, const float* __restrict__ b_out,
    float* __restrict__ out, int* __restrict__ flag)
{
    const int tid = threadIdx.x;
    const float TH = 15.0f - 0.5f;    // margin >> bf16-GEMM error (~0.05)
    const bool silent = (gmax[0] < TH);
    if (silent) {
        for (int i = tid; i < BATCH * OUT_DIM; i += 256)
            out[i] = b_out[i % OUT_DIM];
    }
    if (tid < BATCH) flag[tid] = silent ? 0 : 1;
}

// ============================================================================
// Kernel 3: gated full sequential sim (round-1 structure, known correct).
// Runs only for batches whose flag is set (never, for this data). Also the
// standalone fallback when ws is too small (flag == nullptr -> always run).
// ============================================================================
__global__ __launch_bounds__(256) void rsnn_seq_kernel(
    const int* __restrict__ flag,
    const float* __restrict__ x,
    const float* __restrict__ W_in,
    const float* __restrict__ W_rec,
    const float* __restrict__ asc_amps,
    const float* __restrict__ k_decay,
    const float* __restrict__ W_out,
    const float* __restrict__ b_out,
    const float* __restrict__ in_scale_p,
    const float* __restrict__ out_scale_p,
    float* __restrict__ out)
{
    const int b = blockIdx.x;
    if (flag && flag[b] == 0) return;

    const int tid  = threadIdx.x;
    const int lane = tid & 63;
    const int wave = tid >> 6;
    const bool active = tid < (N_NEURON / 4);
    const int n0 = tid * 4;

    __shared__ ull_t smask[2][16];
    __shared__ float acc_sh[N_NEURON];
    __shared__ float xr[2][IN_DIM];

    const float a_v      = expf(-1.0f / 20.0f);
    const float a_syn    = expf(-1.0f / 5.0f);
    const float a_read   = expf(-1.0f / 20.0f);
    const float one_m_av = 1.0f - a_v;
    const float one_m_ar = 1.0f - a_read;
    const float VR = -60.0f, VTH = -45.0f;
    const float in_scale  = in_scale_p[0];
    const float out_scale = out_scale_p[0];

    float v[4], Ia[4], psc[4], f[4], acc[4], aasc[4], amp[4];
#pragma unroll
    for (int c = 0; c < 4; ++c) {
        v[c] = VR; Ia[c] = 0.f; psc[c] = 0.f; f[c] = 0.f; acc[c] = 0.f;
        aasc[c] = active ? expf(-k_decay[n0 + c]) : 0.f;
        amp[c]  = active ? asc_amps[n0 + c] : 0.f;
    }
    if (tid < 16) { smask[0][tid] = 0ull; smask[1][tid] = 0ull; }

    if (tid < IN_DIM / 4) {
        float4 xv = ((const float4*)(x + (size_t)b * IN_DIM))[tid];
        xr[0][tid * 4 + 0] = xv.x * in_scale; xr[0][tid * 4 + 1] = xv.y * in_scale;
        xr[0][tid * 4 + 2] = xv.z * in_scale; xr[0][tid * 4 + 3] = xv.w * in_scale;
    }
    int prev_any = 0;
    __syncthreads();

    for (int t = 0; t < T_STEPS; ++t) {
        const int cur = t & 1, nxt = cur ^ 1;
        if (t + 1 < T_STEPS && tid < IN_DIM / 4) {
            float4 xv = ((const float4*)(x + (size_t)((t + 1) * BATCH + b) * IN_DIM))[tid];
            xr[nxt][tid * 4 + 0] = xv.x * in_scale; xr[nxt][tid * 4 + 1] = xv.y * in_scale;
            xr[nxt][tid * 4 + 2] = xv.z * in_scale; xr[nxt][tid * 4 + 3] = xv.w * in_scale;
        }
        float4 Icur = make_float4(0.f, 0.f, 0.f, 0.f);
        if (active) {
            float s0 = 0.f, s1 = 0.f, s2 = 0.f, s3 = 0.f;
            const float4* w0 = (const float4*)(W_in + (size_t)(n0 + 0) * IN_DIM);
            const float4* w1 = (const float4*)(W_in + (size_t)(n0 + 1) * IN_DIM);
            const float4* w2 = (const float4*)(W_in + (size_t)(n0 + 2) * IN_DIM);
            const float4* w3 = (const float4*)(W_in + (size_t)(n0 + 3) * IN_DIM);
#pragma unroll 8
            for (int k4 = 0; k4 < IN_DIM / 4; ++k4) {
                float4 xv = *((const float4*)&xr[cur][0] + k4);
                float4 a0 = w0[k4], a1 = w1[k4], a2 = w2[k4], a3 = w3[k4];
                s0 += xv.x * a0.x + xv.y * a0.y + xv.z * a0.z + xv.w * a0.w;
                s1 += xv.x * a1.x + xv.y * a1.y + xv.z * a1.z + xv.w * a1.w;
                s2 += xv.x * a2.x + xv.y * a2.y + xv.z * a2.z + xv.w * a2.w;
                s3 += xv.x * a3.x + xv.y * a3.y + xv.z * a3.z + xv.w * a3.w;
            }
            Icur = make_float4(s0, s1, s2, s3);
        }

#pragma unroll
        for (int c = 0; c < 4; ++c) psc[c] *= a_syn;
        if (prev_any && active) {
#pragma unroll 1
            for (int w = 0; w < 16; ++w) {
                ull_t m = smask[nxt][w];
                while (m) {
                    int bit = __ffsll(m) - 1;
                    m &= m - 1;
                    int npre = ((w >> 2) << 8) + (bit << 2) + (w & 3);
                    const float4 wr = *(const float4*)(W_rec + (size_t)npre * N_NEURON + n0);
                    psc[0] += wr.x; psc[1] += wr.y; psc[2] += wr.z; psc[3] += wr.w;
                }
            }
        }

        float Iv[4] = {Icur.x, Icur.y, Icur.z, Icur.w};
        bool sp[4];
#pragma unroll
        for (int c = 0; c < 4; ++c) {
            float It = Iv[c] + psc[c] + Ia[c];
            float vn = VR + a_v * (v[c] - VR) + one_m_av * It;
            bool s = active && (vn - VTH >= 0.0f);
            float sf = s ? 1.0f : 0.0f;
            vn = vn - (vn - VR) * sf;
            v[c] = vn;
            Ia[c] = aasc[c] * Ia[c] + amp[c] * sf;
            f[c] = (t == 0) ? sf : (a_read * f[c] + one_m_ar * sf);
            if (t >= 199) acc[c] += f[c];
            sp[c] = s;
        }

#pragma unroll
        for (int c = 0; c < 4; ++c) {
            ull_t m = __ballot(sp[c]);
            if (lane == 0) smask[cur][wave * 4 + c] = m;
        }
        int myany = (sp[0] | sp[1] | sp[2] | sp[3]) ? 1 : 0;
        prev_any = __syncthreads_or(myany);
    }

    if (active) {
        acc_sh[n0 + 0] = acc[0]; acc_sh[n0 + 1] = acc[1];
        acc_sh[n0 + 2] = acc[2]; acc_sh[n0 + 3] = acc[3];
    }
    __syncthreads();

    const float inv_cnt = 1.0f / 801.0f;
#pragma unroll
    for (int oo = 0; oo < 5; ++oo) {
        int o = wave * 5 + oo;
        float p = 0.f;
        for (int n = lane; n < N_NEURON; n += 64)
            p += acc_sh[n] * W_out[(size_t)o * N_NEURON + n];
#pragma unroll
        for (int off = 32; off > 0; off >>= 1)
            p += __shfl_down(p, off, 64);
        if (lane == 0)
            out[b * OUT_DIM + o] = out_scale * (p * inv_cnt) + b_out[o];
    }
}

// ============================================================================
extern "C" void kernel_launch(void* const* d_in, const int* in_sizes, int n_in,
                              void* d_out, int out_size, void* d_ws, size_t ws_size,
                              hipStream_t stream)
{
    const float* x         = (const float*)d_in[0];
    const float* W_in      = (const float*)d_in[1];
    const float* W_rec     = (const float*)d_in[2];
    const float* asc_amps  = (const float*)d_in[3];
    const float* k_decay   = (const float*)d_in[4];
    const float* W_out     = (const float*)d_in[5];
    const float* b_out     = (const float*)d_in[6];
    const float* in_scale  = (const float*)d_in[7];
    const float* out_scale = (const float*)d_in[8];
    float* out = (float*)d_out;

    if (ws_size >= WS_NEED) {
        ushort_t* Wb   = (ushort_t*)((char*)d_ws + OFF_WB);
        float*    gmax = (float*)((char*)d_ws + OFF_GMAX);
        int*      flag = (int*)((char*)d_ws + OFF_FLAG);
        conv_wb_kernel<<<NWP4 / 256, 256, 0, stream>>>(W_in, Wb, gmax);
        maxgemm_kernel<<<dim3(250, 4), 256, 0, stream>>>(x, Wb, in_scale, gmax);
        resolve_kernel<<<1, 256, 0, stream>>>(gmax, b_out, out, flag);
        rsnn_seq_kernel<<<BATCH, 256, 0, stream>>>(
            flag, x, W_in, W_rec, asc_amps, k_decay, W_out, b_out,
            in_scale, out_scale, out);
    } else {
        rsnn_seq_kernel<<<BATCH, 256, 0, stream>>>(
            nullptr, x, W_in, W_rec, asc_amps, k_decay, W_out, b_out,
            in_scale, out_scale, out);
    }
}